// Round 8
// baseline (525.489 us; speedup 1.0000x reference)
//
#include <hip/hip_runtime.h>

#define CIN 64
#define COUT 128
#define NC 64        // conv stat buckets
#define NSB 32       // skip stat buckets
#define LDT 132      // padded LDS row stride (dwords)
#define SKB 256      // skip role blocks

typedef __bf16 bf16x8 __attribute__((ext_vector_type(8)));
typedef float  f32x4  __attribute__((ext_vector_type(4)));

// ---------------------------------------------------------------------------
// Fused prep: role-dispatch on blockIdx.x.
//  A: feats fp32 -> bf16    B: weight frag pack    C: tap scatter
//  D: skip inverse map      tail: fb zero row + msplit bsearch
// ---------------------------------------------------------------------------
__global__ __launch_bounds__(256) void prep_kernel(
    const float* __restrict__ feats, __bf16* __restrict__ fb,
    const float* __restrict__ Wc, const float* __restrict__ Ws, __bf16* __restrict__ wf,
    const int* __restrict__ cin_idx, const int* __restrict__ cout_idx, int* __restrict__ tap_in,
    const int* __restrict__ sout, int* __restrict__ inv,
    const int* __restrict__ boo, int* __restrict__ msplit,
    int total8, int P, int cpb, int Ls, int N, int M,
    int nbA, int nbAB, int nbABC, int nbABCD)
{
    const int bid = blockIdx.x, t = threadIdx.x;
    if (bid < nbA) {                                  // A: feats -> bf16
        const int i = bid * 256 + t;
        if (i >= total8) return;
        const int i8 = i * 8;
        const float4 x0 = *(const float4*)(feats + i8);
        const float4 x1 = *(const float4*)(feats + i8 + 4);
        bf16x8 v;
        v[0] = (__bf16)x0.x; v[1] = (__bf16)x0.y; v[2] = (__bf16)x0.z; v[3] = (__bf16)x0.w;
        v[4] = (__bf16)x1.x; v[5] = (__bf16)x1.y; v[6] = (__bf16)x1.z; v[7] = (__bf16)x1.w;
        *(bf16x8*)(fb + i8) = v;
    } else if (bid < nbAB) {                          // B: wfrag pack
        const int id = (bid - nbA) * 256 + t;
        if (id >= 160 * 64) return;
        const int f = id >> 6, lane = id & 63;
        const float* W; int r;
        if (f < 144) { W = Wc + (size_t)(f >> 4) * CIN * COUT; r = f & 15; }
        else         { W = Ws;                                  r = f - 144; }
        const int c = r >> 1, s = r & 1;
        const int kbase = s * 32 + (lane >> 4) * 8;
        const int col = c * 16 + (lane & 15);
        bf16x8 v;
#pragma unroll
        for (int j = 0; j < 8; ++j) v[j] = (__bf16)W[(size_t)(kbase + j) * COUT + col];
        *(bf16x8*)(wf + ((size_t)f * 64 + lane) * 8) = v;
    } else if (bid < nbABC) {                         // C: tap scatter
        const int c = bid - nbAB;
        const int k = c / cpb;
        const int e = (c - k * cpb) * 256 + t;
        if (e >= P) return;
        const int oo = cout_idx[(size_t)k * P + e];
        if (oo < M) tap_in[(size_t)k * M + oo] = cin_idx[(size_t)k * P + e];
    } else if (bid < nbABCD) {                        // D: inverse skip map
        const int i = (bid - nbABC) * 256 + t;
        if (i < Ls) inv[sout[i]] = i;
    } else {                                          // tail: zero row + msplit
        if (t < 64) fb[(size_t)N * CIN + t] = (__bf16)0.f;
        if (t == 0) {
            int lo = 0, hi = M;
            while (lo < hi) { const int mid = (lo + hi) >> 1; if (boo[mid] < 1) lo = mid + 1; else hi = mid; }
            msplit[0] = lo;
        }
    }
}

// ---------------------------------------------------------------------------
// Fused conv + skip. Blocks [0,SKB): skip gather-GEMM. Blocks [SKB, SKB+ntiles):
// conv, 64 rows/block, g-outer pipeline: 9 idx loads -> 18 A loads -> 36 MFMA.
// Epilogue: padded-LDS transpose, coalesced store, bucketed stats.
// ---------------------------------------------------------------------------
__global__ __launch_bounds__(256, 4) void conv_mfma_kernel(
    const __bf16* __restrict__ fb,      // [N+1][CIN], row N zeros
    const __bf16* __restrict__ wf,
    const int* __restrict__ tap_in,     // [9][M], 0x7f sentinel
    const int* __restrict__ sin_idx,
    const int* __restrict__ msplit_p,
    float* __restrict__ out,
    float* __restrict__ G,
    float* __restrict__ zstats,         // [NC*384 conv | NSB*256 skip]
    int N, int M, int Ls)
{
    __shared__ float acc[64 * LDT];
    __shared__ float sred[384];
    const int t = threadIdx.x, lane = t & 63, wv = t >> 6;
    const int arow = lane & 15, apart = lane >> 4;

    if (blockIdx.x < SKB) {
        // ---------------- skip role ----------------
        const __bf16* wk = wf + ((size_t)144 * 64 + lane) * 8;
        const bf16x8 b00 = *(const bf16x8*)(wk + (size_t)(wv * 4 + 0) * 512);
        const bf16x8 b01 = *(const bf16x8*)(wk + (size_t)(wv * 4 + 1) * 512);
        const bf16x8 b10 = *(const bf16x8*)(wk + (size_t)(wv * 4 + 2) * 512);
        const bf16x8 b11 = *(const bf16x8*)(wk + (size_t)(wv * 4 + 3) * 512);
        const int colA = wv * 32 + arow;
        const int colB = colA + 16;

        float s1A = 0.f, s2A = 0.f, s1B = 0.f, s2B = 0.f;
        const int ngroups = (Ls + 15) >> 4;
        for (int g = blockIdx.x; g < ngroups; g += SKB) {
            const int e0 = g * 16;
            const int ea = e0 + arow;
            const int ii = (ea < Ls) ? sin_idx[ea] : 0;
            const __bf16* fr = fb + (size_t)ii * CIN + apart * 8;
            const bf16x8 a0 = *(const bf16x8*)fr;
            const bf16x8 a1 = *(const bf16x8*)(fr + 32);

            f32x4 dA = {0.f,0.f,0.f,0.f};
            f32x4 dB = {0.f,0.f,0.f,0.f};
            dA = __builtin_amdgcn_mfma_f32_16x16x32_bf16(a0, b00, dA, 0, 0, 0);
            dA = __builtin_amdgcn_mfma_f32_16x16x32_bf16(a1, b01, dA, 0, 0, 0);
            dB = __builtin_amdgcn_mfma_f32_16x16x32_bf16(a0, b10, dB, 0, 0, 0);
            dB = __builtin_amdgcn_mfma_f32_16x16x32_bf16(a1, b11, dB, 0, 0, 0);

            const int er = e0 + apart * 4;
#pragma unroll
            for (int j = 0; j < 4; ++j) {
                if (er + j < Ls) {
                    const float vA = dA[j], vB = dB[j];
                    G[(size_t)(er + j) * COUT + colA] = vA;
                    G[(size_t)(er + j) * COUT + colB] = vB;
                    s1A += vA; s2A += vA * vA;
                    s1B += vB; s2B += vB * vB;
                }
            }
        }
        s1A += __shfl_xor(s1A, 16); s1A += __shfl_xor(s1A, 32);
        s2A += __shfl_xor(s2A, 16); s2A += __shfl_xor(s2A, 32);
        s1B += __shfl_xor(s1B, 16); s1B += __shfl_xor(s1B, 32);
        s2B += __shfl_xor(s2B, 16); s2B += __shfl_xor(s2B, 32);
        if (apart == 0) {
            sred[colA] = s1A; sred[colB] = s1B;
            sred[128 + colA] = s2A; sred[128 + colB] = s2B;
        }
        __syncthreads();
        float* bucket = zstats + NC * 384 + (size_t)(blockIdx.x & (NSB - 1)) * 256;
        if (t < 128) {
            atomicAdd(&bucket[t],       sred[t]);
            atomicAdd(&bucket[128 + t], sred[128 + t]);
        }
        return;
    }

    // ---------------- conv role ----------------
    const int m0 = (blockIdx.x - SKB) * 64;
    const int msplit = msplit_p[0];
    for (int i = t; i < 384; i += 256) sred[i] = 0.f;

    const __bf16* wbase = wf + ((size_t)(wv * 4) * 64 + lane) * 8;

#pragma unroll 1
    for (int g = 0; g < 4; ++g) {
        const int mr = m0 + g * 16 + arow;
        int idx[9];
#pragma unroll
        for (int k = 0; k < 9; ++k) {
            int v = (mr < M) ? tap_in[(size_t)k * M + mr] : N;
            idx[k] = (v > N) ? N : v;       // 0x7f sentinel -> zero row
        }
        bf16x8 A0[9], A1[9];
#pragma unroll
        for (int k = 0; k < 9; ++k) {
            const __bf16* f0 = fb + (size_t)idx[k] * CIN + apart * 8;
            A0[k] = *(const bf16x8*)f0;
            A1[k] = *(const bf16x8*)(f0 + 32);
        }
        f32x4 d0 = {0.f,0.f,0.f,0.f}, d1 = {0.f,0.f,0.f,0.f};
#pragma unroll
        for (int k = 0; k < 9; ++k) {
            const __bf16* wb = wbase + (size_t)k * (16 * 64 * 8);
            const bf16x8 b00 = *(const bf16x8*)(wb + 0 * 512);
            const bf16x8 b01 = *(const bf16x8*)(wb + 1 * 512);
            const bf16x8 b10 = *(const bf16x8*)(wb + 2 * 512);
            const bf16x8 b11 = *(const bf16x8*)(wb + 3 * 512);
            d0 = __builtin_amdgcn_mfma_f32_16x16x32_bf16(A0[k], b00, d0, 0, 0, 0);
            d0 = __builtin_amdgcn_mfma_f32_16x16x32_bf16(A1[k], b01, d0, 0, 0, 0);
            d1 = __builtin_amdgcn_mfma_f32_16x16x32_bf16(A0[k], b10, d1, 0, 0, 0);
            d1 = __builtin_amdgcn_mfma_f32_16x16x32_bf16(A1[k], b11, d1, 0, 0, 0);
        }
        // padded-LDS scatter (2-way banks = free)
#pragma unroll
        for (int j = 0; j < 4; ++j) {
            const int r = g * 16 + apart * 4 + j;
            acc[r * LDT + wv * 32 + arow]      = d0[j];
            acc[r * LDT + wv * 32 + 16 + arow] = d1[j];
        }
    }
    __syncthreads();

    // coalesced store + fused BN stats
    const int c4 = (t & 31) * 4;
    const int r0 = t >> 5;
    float st_s[4] = {0.f,0.f,0.f,0.f};
    float st_q[4] = {0.f,0.f,0.f,0.f};
    float st_0[4] = {0.f,0.f,0.f,0.f};
#pragma unroll
    for (int i = 0; i < 8; ++i) {
        const int r = r0 + i * 8;
        const int m = m0 + r;
        if (m < M) {
            const f32x4 v = *(const f32x4*)&acc[r * LDT + c4];
            *(f32x4*)(out + (size_t)m * COUT + c4) = v;
            const bool b0 = m < msplit;
#pragma unroll
            for (int cc = 0; cc < 4; ++cc) {
                st_s[cc] += v[cc];
                st_q[cc] += v[cc] * v[cc];
                if (b0) st_0[cc] += v[cc];
            }
        }
    }
#pragma unroll
    for (int cc = 0; cc < 4; ++cc) {
        atomicAdd(&sred[c4 + cc],       st_0[cc]);
        atomicAdd(&sred[128 + c4 + cc], st_s[cc] - st_0[cc]);
        atomicAdd(&sred[256 + c4 + cc], st_q[cc]);
    }
    __syncthreads();
    float* bucket = zstats + (size_t)(blockIdx.x & (NC - 1)) * 384;
    if (t < 128) {
        atomicAdd(&bucket[t],       sred[t]);
        atomicAdd(&bucket[128 + t], sred[128 + t]);
        atomicAdd(&bucket[256 + t], sred[256 + t]);
    }
}

// ---------------------------------------------------------------------------
// Single-block: reduce buckets, BN params (main + skip), SE MLP.
// ---------------------------------------------------------------------------
__global__ __launch_bounds__(128) void params_kernel(
    const float* __restrict__ zstats,
    const int* __restrict__ msplit_p,
    const float* __restrict__ gamma, const float* __restrict__ beta,
    const float* __restrict__ sgamma, const float* __restrict__ sbeta,
    const float* __restrict__ fc1, const float* __restrict__ fc2,
    float* __restrict__ scale, float* __restrict__ shift,
    float* __restrict__ sscale, float* __restrict__ sshift,
    float* __restrict__ attn,
    int Ls, int M)
{
    __shared__ float desc[2][COUT];
    __shared__ float hid[2][8];
    const int ch = threadIdx.x;

    float s0 = 0.f, s1 = 0.f, q = 0.f;
    for (int b = 0; b < NC; ++b) {
        const float* st = zstats + (size_t)b * 384;
        s0 += st[ch]; s1 += st[128 + ch]; q += st[256 + ch];
    }
    float ss = 0.f, sq = 0.f;
    const float* sk = zstats + NC * 384;
    for (int b = 0; b < NSB; ++b) {
        ss += sk[(size_t)b * 256 + ch];
        sq += sk[(size_t)b * 256 + 128 + ch];
    }

    const float c0 = (float)msplit_p[0], c1 = (float)M - c0;
    const float Mf = (float)M;
    const float mu  = (s0 + s1) / Mf;
    const float var = q / Mf - mu * mu;
    const float rs  = rsqrtf(var + 1e-5f);
    const float sc  = rs * gamma[ch];
    const float sh  = beta[ch] - mu * sc;
    scale[ch] = sc;
    shift[ch] = sh;
    desc[0][ch] = (s0 / c0) * sc + sh;
    desc[1][ch] = (s1 / c1) * sc + sh;

    const float lsf  = (float)Ls;
    const float mus  = ss / lsf;
    const float vars = sq / lsf - mus * mus;
    const float rss  = rsqrtf(vars + 1e-5f);
    const float ssc  = rss * sgamma[ch];
    sscale[ch] = ssc;
    sshift[ch] = sbeta[ch] - mus * ssc;

    __syncthreads();
    if (ch < 16) {
        const int b = ch >> 3, h = ch & 7;
        float a = 0.f;
        for (int c = 0; c < COUT; ++c) a += desc[b][c] * fc1[c * 8 + h];
        hid[b][h] = fmaxf(a, 0.f);
    }
    __syncthreads();
    for (int b = 0; b < 2; ++b) {
        float a = 0.f;
        for (int h = 0; h < 8; ++h) a += hid[b][h] * fc2[h * COUT + ch];
        attn[b * COUT + ch] = 1.f / (1.f + expf(-a));
    }
}

// ---------------------------------------------------------------------------
// Epilogue: out = relu(bn(x)*attn[b] + bn_skip(G[inv])), float4-vectorized.
// ---------------------------------------------------------------------------
__global__ __launch_bounds__(256) void final_kernel(
    float* __restrict__ out,
    const float* __restrict__ G,
    const int* __restrict__ inv_skip,
    const int* __restrict__ batch_of_out,
    const float* __restrict__ scale, const float* __restrict__ shift,
    const float* __restrict__ sscale, const float* __restrict__ sshift,
    const float* __restrict__ attn,
    int M)
{
    const int t  = threadIdx.x;
    const int c4 = (t & 31) * 4;
    const int rw = t >> 5;
    const float4 sc  = *(const float4*)&scale[c4];
    const float4 sh  = *(const float4*)&shift[c4];
    const float4 ssc = *(const float4*)&sscale[c4];
    const float4 ssh = *(const float4*)&sshift[c4];
    const float4 at0 = *(const float4*)&attn[c4];
    const float4 at1 = *(const float4*)&attn[COUT + c4];

    for (int m = blockIdx.x * 8 + rw; m < M; m += gridDim.x * 8) {
        const float4 x = *(const float4*)&out[(size_t)m * COUT + c4];
        const int b = batch_of_out[m];
        const int j = inv_skip[m];
        const float4 av = b ? at1 : at0;
        float4 y;
        y.x = (x.x * sc.x + sh.x) * av.x;
        y.y = (x.y * sc.y + sh.y) * av.y;
        y.z = (x.z * sc.z + sh.z) * av.z;
        y.w = (x.w * sc.w + sh.w) * av.w;
        if (j >= 0) {
            const float4 g = *(const float4*)&G[(size_t)j * COUT + c4];
            y.x += g.x * ssc.x + ssh.x;
            y.y += g.y * ssc.y + ssh.y;
            y.z += g.z * ssc.z + ssh.z;
            y.w += g.w * ssc.w + ssh.w;
        }
        y.x = y.x > 0.f ? y.x : 0.f;
        y.y = y.y > 0.f ? y.y : 0.f;
        y.z = y.z > 0.f ? y.z : 0.f;
        y.w = y.w > 0.f ? y.w : 0.f;
        *(float4*)&out[(size_t)m * COUT + c4] = y;
    }
}

extern "C" void kernel_launch(void* const* d_in, const int* in_sizes, int n_in,
                              void* d_out, int out_size, void* d_ws, size_t ws_size,
                              hipStream_t stream)
{
    const float* feats  = (const float*)d_in[0];
    const float* Wc     = (const float*)d_in[1];
    const float* Wsk    = (const float*)d_in[2];
    const float* gamma  = (const float*)d_in[3];
    const float* beta   = (const float*)d_in[4];
    const float* sgamma = (const float*)d_in[5];
    const float* sbeta  = (const float*)d_in[6];
    const float* fc1    = (const float*)d_in[7];
    const float* fc2    = (const float*)d_in[8];
    const int* cin_idx  = (const int*)d_in[9];
    const int* cout_idx = (const int*)d_in[10];
    const int* sin_idx  = (const int*)d_in[11];
    const int* sout_idx = (const int*)d_in[12];
    const int* boo      = (const int*)d_in[13];

    const int N  = in_sizes[0] / CIN;
    const int P  = in_sizes[9] / 9;
    const int Ls = in_sizes[11];
    const int M  = in_sizes[13];
    const int ntiles = (M + 63) / 64;

    float* out = (float*)d_out;

    // workspace layout
    char* ws = (char*)d_ws;
    __bf16* fb = (__bf16*)ws;                       // (N+1) x CIN
    size_t off = (size_t)(N + 1) * CIN * sizeof(__bf16);
    off = (off + 255) & ~(size_t)255;
    __bf16* wfrag = (__bf16*)(ws + off);
    off += (size_t)160 * 64 * 8 * sizeof(__bf16);
    off = (off + 255) & ~(size_t)255;
    int* tap_in = (int*)(ws + off);                 // 9 x M
    off += (size_t)9 * M * sizeof(int);
    off = (off + 255) & ~(size_t)255;
    float* G = (float*)(ws + off);                  // Ls x COUT
    off += (size_t)Ls * COUT * sizeof(float);
    int* inv_skip = (int*)(ws + off);               // M
    off += (size_t)M * sizeof(int);
    off = (off + 255) & ~(size_t)255;
    float* zstats = (float*)(ws + off);             // NC*384 + NSB*256
    off += (size_t)(NC * 384 + NSB * 256) * sizeof(float);
    int* msplit = (int*)(ws + off);
    off += 256;
    float* params = (float*)(ws + off);
    float* scale = params, *shift = params + 128;
    float* sscale = params + 256, *sshift = params + 384, *attn = params + 512;

    hipMemsetAsync(zstats, 0, (size_t)(NC * 384 + NSB * 256) * sizeof(float), stream);
    hipMemsetAsync(inv_skip, 0xFF, (size_t)M * sizeof(int), stream);      // -1
    hipMemsetAsync(tap_in, 0x7F, (size_t)9 * M * sizeof(int), stream);    // big sentinel

    // fused prep
    const int total8 = N * CIN / 8;
    const int nbA = (total8 + 255) / 256;
    const int nbB = (160 * 64 + 255) / 256;
    const int cpb = (P + 255) / 256;
    const int nbAB = nbA + nbB;
    const int nbABC = nbAB + 9 * cpb;
    const int nbABCD = nbABC + (Ls + 255) / 256;
    prep_kernel<<<nbABCD + 1, 256, 0, stream>>>(
        feats, fb, Wc, Wsk, wfrag, cin_idx, cout_idx, tap_in, sout_idx, inv_skip,
        boo, msplit, total8, P, cpb, Ls, N, M, nbA, nbAB, nbABC, nbABCD);

    conv_mfma_kernel<<<SKB + ntiles, 256, 0, stream>>>(
        fb, wfrag, tap_in, sin_idx, msplit, out, G, zstats, N, M, Ls);

    params_kernel<<<1, 128, 0, stream>>>(
        zstats, msplit, gamma, beta, sgamma, sbeta, fc1, fc2,
        scale, shift, sscale, sshift, attn, Ls, M);

    final_kernel<<<2048, 256, 0, stream>>>(
        out, G, inv_skip, boo, scale, shift, sscale, sshift, attn, M);
}

// Round 9
// 278.117 us; speedup vs baseline: 1.8895x; 1.8895x over previous
//
#include <hip/hip_runtime.h>

#define CIN 64
#define COUT 128
#define NC 64        // conv stat buckets
#define NSB 32       // skip stat buckets
#define LDT 132      // padded LDS row stride (dwords)
#define SKB 256      // skip role blocks

typedef __bf16 bf16x8 __attribute__((ext_vector_type(8)));
typedef float  f32x4  __attribute__((ext_vector_type(4)));

// ---------------------------------------------------------------------------
// Fused prep: role-dispatch on blockIdx.x.
//  A: feats fp32 -> bf16    B: weight frag pack    C: tap scatter
//  D: skip inverse map      tail: fb zero row + msplit bsearch
// ---------------------------------------------------------------------------
__global__ __launch_bounds__(256) void prep_kernel(
    const float* __restrict__ feats, __bf16* __restrict__ fb,
    const float* __restrict__ Wc, const float* __restrict__ Ws, __bf16* __restrict__ wf,
    const int* __restrict__ cin_idx, const int* __restrict__ cout_idx, int* __restrict__ tap_in,
    const int* __restrict__ sout, int* __restrict__ inv,
    const int* __restrict__ boo, int* __restrict__ msplit,
    int total8, int P, int cpb, int Ls, int N, int M,
    int nbA, int nbAB, int nbABC, int nbABCD)
{
    const int bid = blockIdx.x, t = threadIdx.x;
    if (bid < nbA) {                                  // A: feats -> bf16
        const int i = bid * 256 + t;
        if (i >= total8) return;
        const int i8 = i * 8;
        const float4 x0 = *(const float4*)(feats + i8);
        const float4 x1 = *(const float4*)(feats + i8 + 4);
        bf16x8 v;
        v[0] = (__bf16)x0.x; v[1] = (__bf16)x0.y; v[2] = (__bf16)x0.z; v[3] = (__bf16)x0.w;
        v[4] = (__bf16)x1.x; v[5] = (__bf16)x1.y; v[6] = (__bf16)x1.z; v[7] = (__bf16)x1.w;
        *(bf16x8*)(fb + i8) = v;
    } else if (bid < nbAB) {                          // B: wfrag pack
        const int id = (bid - nbA) * 256 + t;
        if (id >= 160 * 64) return;
        const int f = id >> 6, lane = id & 63;
        const float* W; int r;
        if (f < 144) { W = Wc + (size_t)(f >> 4) * CIN * COUT; r = f & 15; }
        else         { W = Ws;                                  r = f - 144; }
        const int c = r >> 1, s = r & 1;
        const int kbase = s * 32 + (lane >> 4) * 8;
        const int col = c * 16 + (lane & 15);
        bf16x8 v;
#pragma unroll
        for (int j = 0; j < 8; ++j) v[j] = (__bf16)W[(size_t)(kbase + j) * COUT + col];
        *(bf16x8*)(wf + ((size_t)f * 64 + lane) * 8) = v;
    } else if (bid < nbABC) {                         // C: tap scatter
        const int c = bid - nbAB;
        const int k = c / cpb;
        const int e = (c - k * cpb) * 256 + t;
        if (e >= P) return;
        const int oo = cout_idx[(size_t)k * P + e];
        if (oo < M) tap_in[(size_t)k * M + oo] = cin_idx[(size_t)k * P + e];
    } else if (bid < nbABCD) {                        // D: inverse skip map
        const int i = (bid - nbABC) * 256 + t;
        if (i < Ls) inv[sout[i]] = i;
    } else {                                          // tail: zero row + msplit
        if (t < 64) fb[(size_t)N * CIN + t] = (__bf16)0.f;
        if (t == 0) {
            int lo = 0, hi = M;
            while (lo < hi) { const int mid = (lo + hi) >> 1; if (boo[mid] < 1) lo = mid + 1; else hi = mid; }
            msplit[0] = lo;
        }
    }
}

// ---------------------------------------------------------------------------
// Fused conv + skip. Blocks [0,SKB): skip gather-GEMM. Blocks [SKB,...): conv.
// Conv: 64 rows/block, 4 col-split waves. k-outer; per k the 4 row-groups'
// loads are batched (idx prefetched one k ahead) for memory-level parallelism,
// then 16 MFMAs. Epilogue: padded-LDS transpose, coalesced store, stats.
// ---------------------------------------------------------------------------
__global__ __launch_bounds__(256, 4) void conv_mfma_kernel(
    const __bf16* __restrict__ fb,      // [N+1][CIN], row N zeros
    const __bf16* __restrict__ wf,
    const int* __restrict__ tap_in,     // [9][M], 0x7f sentinel
    const int* __restrict__ sin_idx,
    const int* __restrict__ msplit_p,
    float* __restrict__ out,
    float* __restrict__ G,
    float* __restrict__ zstats,         // [NC*384 conv | NSB*256 skip]
    int N, int M, int Ls)
{
    __shared__ float acc[64 * LDT];
    __shared__ float sred[384];
    const int t = threadIdx.x, lane = t & 63, wv = t >> 6;
    const int arow = lane & 15, apart = lane >> 4;

    if (blockIdx.x < SKB) {
        // ---------------- skip role ----------------
        const __bf16* wk = wf + ((size_t)144 * 64 + lane) * 8;
        const bf16x8 b00 = *(const bf16x8*)(wk + (size_t)(wv * 4 + 0) * 512);
        const bf16x8 b01 = *(const bf16x8*)(wk + (size_t)(wv * 4 + 1) * 512);
        const bf16x8 b10 = *(const bf16x8*)(wk + (size_t)(wv * 4 + 2) * 512);
        const bf16x8 b11 = *(const bf16x8*)(wk + (size_t)(wv * 4 + 3) * 512);
        const int colA = wv * 32 + arow;
        const int colB = colA + 16;

        float s1A = 0.f, s2A = 0.f, s1B = 0.f, s2B = 0.f;
        const int ngroups = (Ls + 15) >> 4;
        for (int g = blockIdx.x; g < ngroups; g += SKB) {
            const int e0 = g * 16;
            const int ea = e0 + arow;
            const int ii = (ea < Ls) ? sin_idx[ea] : 0;
            const __bf16* fr = fb + (size_t)ii * CIN + apart * 8;
            const bf16x8 a0 = *(const bf16x8*)fr;
            const bf16x8 a1 = *(const bf16x8*)(fr + 32);

            f32x4 dA = {0.f,0.f,0.f,0.f};
            f32x4 dB = {0.f,0.f,0.f,0.f};
            dA = __builtin_amdgcn_mfma_f32_16x16x32_bf16(a0, b00, dA, 0, 0, 0);
            dA = __builtin_amdgcn_mfma_f32_16x16x32_bf16(a1, b01, dA, 0, 0, 0);
            dB = __builtin_amdgcn_mfma_f32_16x16x32_bf16(a0, b10, dB, 0, 0, 0);
            dB = __builtin_amdgcn_mfma_f32_16x16x32_bf16(a1, b11, dB, 0, 0, 0);

            const int er = e0 + apart * 4;
#pragma unroll
            for (int j = 0; j < 4; ++j) {
                if (er + j < Ls) {
                    const float vA = dA[j], vB = dB[j];
                    G[(size_t)(er + j) * COUT + colA] = vA;
                    G[(size_t)(er + j) * COUT + colB] = vB;
                    s1A += vA; s2A += vA * vA;
                    s1B += vB; s2B += vB * vB;
                }
            }
        }
        s1A += __shfl_xor(s1A, 16); s1A += __shfl_xor(s1A, 32);
        s2A += __shfl_xor(s2A, 16); s2A += __shfl_xor(s2A, 32);
        s1B += __shfl_xor(s1B, 16); s1B += __shfl_xor(s1B, 32);
        s2B += __shfl_xor(s2B, 16); s2B += __shfl_xor(s2B, 32);
        if (apart == 0) {
            sred[colA] = s1A; sred[colB] = s1B;
            sred[128 + colA] = s2A; sred[128 + colB] = s2B;
        }
        __syncthreads();
        float* bucket = zstats + NC * 384 + (size_t)(blockIdx.x & (NSB - 1)) * 256;
        if (t < 128) {
            atomicAdd(&bucket[t],       sred[t]);
            atomicAdd(&bucket[128 + t], sred[128 + t]);
        }
        return;
    }

    // ---------------- conv role ----------------
    const int m0 = (blockIdx.x - SKB) * 64;
    const int msplit = msplit_p[0];
    for (int i = t; i < 384; i += 256) sred[i] = 0.f;

    f32x4 d0[4], d1[4];
#pragma unroll
    for (int g = 0; g < 4; ++g) {
        d0[g] = (f32x4){0.f,0.f,0.f,0.f};
        d1[g] = (f32x4){0.f,0.f,0.f,0.f};
    }

    int idxc[4], idxn[4];
#pragma unroll
    for (int g = 0; g < 4; ++g) {
        const int mrow = m0 + g * 16 + arow;
        const int v = (mrow < M) ? tap_in[mrow] : N;      // k = 0
        idxc[g] = (v > N) ? N : v;
    }

#pragma unroll
    for (int k = 0; k < 9; ++k) {
        // prefetch next-k indices (breaks idx->A serial chain)
        if (k < 8) {
#pragma unroll
            for (int g = 0; g < 4; ++g) {
                const int mrow = m0 + g * 16 + arow;
                const int v = (mrow < M) ? tap_in[(size_t)(k + 1) * M + mrow] : N;
                idxn[g] = (v > N) ? N : v;
            }
        }
        // batched A loads for this k (8 independent 16B loads)
        bf16x8 A0[4], A1[4];
#pragma unroll
        for (int g = 0; g < 4; ++g) {
            const __bf16* f0 = fb + (size_t)idxc[g] * CIN + apart * 8;
            A0[g] = *(const bf16x8*)f0;
            A1[g] = *(const bf16x8*)(f0 + 32);
        }
        // B frags (L2-resident, loaded once per k)
        const __bf16* wb = wf + ((size_t)((k * 16 + wv * 4) * 64) + lane) * 8;
        const bf16x8 b00 = *(const bf16x8*)(wb + 0 * 512);
        const bf16x8 b01 = *(const bf16x8*)(wb + 1 * 512);
        const bf16x8 b10 = *(const bf16x8*)(wb + 2 * 512);
        const bf16x8 b11 = *(const bf16x8*)(wb + 3 * 512);
#pragma unroll
        for (int g = 0; g < 4; ++g) {
            d0[g] = __builtin_amdgcn_mfma_f32_16x16x32_bf16(A0[g], b00, d0[g], 0, 0, 0);
            d0[g] = __builtin_amdgcn_mfma_f32_16x16x32_bf16(A1[g], b01, d0[g], 0, 0, 0);
            d1[g] = __builtin_amdgcn_mfma_f32_16x16x32_bf16(A0[g], b10, d1[g], 0, 0, 0);
            d1[g] = __builtin_amdgcn_mfma_f32_16x16x32_bf16(A1[g], b11, d1[g], 0, 0, 0);
        }
#pragma unroll
        for (int g = 0; g < 4; ++g) idxc[g] = idxn[g];
    }

    // padded-LDS scatter (2-way banks = free)
#pragma unroll
    for (int g = 0; g < 4; ++g)
#pragma unroll
        for (int j = 0; j < 4; ++j) {
            const int r = g * 16 + apart * 4 + j;
            acc[r * LDT + wv * 32 + arow]      = d0[g][j];
            acc[r * LDT + wv * 32 + 16 + arow] = d1[g][j];
        }
    __syncthreads();

    // coalesced store + fused BN stats
    const int c4 = (t & 31) * 4;
    const int r0 = t >> 5;
    float st_s[4] = {0.f,0.f,0.f,0.f};
    float st_q[4] = {0.f,0.f,0.f,0.f};
    float st_0[4] = {0.f,0.f,0.f,0.f};
#pragma unroll
    for (int i = 0; i < 8; ++i) {
        const int r = r0 + i * 8;
        const int m = m0 + r;
        if (m < M) {
            const f32x4 v = *(const f32x4*)&acc[r * LDT + c4];
            *(f32x4*)(out + (size_t)m * COUT + c4) = v;
            const bool b0 = m < msplit;
#pragma unroll
            for (int cc = 0; cc < 4; ++cc) {
                st_s[cc] += v[cc];
                st_q[cc] += v[cc] * v[cc];
                if (b0) st_0[cc] += v[cc];
            }
        }
    }
#pragma unroll
    for (int cc = 0; cc < 4; ++cc) {
        atomicAdd(&sred[c4 + cc],       st_0[cc]);
        atomicAdd(&sred[128 + c4 + cc], st_s[cc] - st_0[cc]);
        atomicAdd(&sred[256 + c4 + cc], st_q[cc]);
    }
    __syncthreads();
    float* bucket = zstats + (size_t)(blockIdx.x & (NC - 1)) * 384;
    if (t < 128) {
        atomicAdd(&bucket[t],       sred[t]);
        atomicAdd(&bucket[128 + t], sred[128 + t]);
        atomicAdd(&bucket[256 + t], sred[256 + t]);
    }
}

// ---------------------------------------------------------------------------
// Single-block: reduce buckets, BN params (main + skip), SE MLP.
// ---------------------------------------------------------------------------
__global__ __launch_bounds__(128) void params_kernel(
    const float* __restrict__ zstats,
    const int* __restrict__ msplit_p,
    const float* __restrict__ gamma, const float* __restrict__ beta,
    const float* __restrict__ sgamma, const float* __restrict__ sbeta,
    const float* __restrict__ fc1, const float* __restrict__ fc2,
    float* __restrict__ scale, float* __restrict__ shift,
    float* __restrict__ sscale, float* __restrict__ sshift,
    float* __restrict__ attn,
    int Ls, int M)
{
    __shared__ float desc[2][COUT];
    __shared__ float hid[2][8];
    const int ch = threadIdx.x;

    float s0 = 0.f, s1 = 0.f, q = 0.f;
    for (int b = 0; b < NC; ++b) {
        const float* st = zstats + (size_t)b * 384;
        s0 += st[ch]; s1 += st[128 + ch]; q += st[256 + ch];
    }
    float ss = 0.f, sq = 0.f;
    const float* sk = zstats + NC * 384;
    for (int b = 0; b < NSB; ++b) {
        ss += sk[(size_t)b * 256 + ch];
        sq += sk[(size_t)b * 256 + 128 + ch];
    }

    const float c0 = (float)msplit_p[0], c1 = (float)M - c0;
    const float Mf = (float)M;
    const float mu  = (s0 + s1) / Mf;
    const float var = q / Mf - mu * mu;
    const float rs  = rsqrtf(var + 1e-5f);
    const float sc  = rs * gamma[ch];
    const float sh  = beta[ch] - mu * sc;
    scale[ch] = sc;
    shift[ch] = sh;
    desc[0][ch] = (s0 / c0) * sc + sh;
    desc[1][ch] = (s1 / c1) * sc + sh;

    const float lsf  = (float)Ls;
    const float mus  = ss / lsf;
    const float vars = sq / lsf - mus * mus;
    const float rss  = rsqrtf(vars + 1e-5f);
    const float ssc  = rss * sgamma[ch];
    sscale[ch] = ssc;
    sshift[ch] = sbeta[ch] - mus * ssc;

    __syncthreads();
    if (ch < 16) {
        const int b = ch >> 3, h = ch & 7;
        float a = 0.f;
        for (int c = 0; c < COUT; ++c) a += desc[b][c] * fc1[c * 8 + h];
        hid[b][h] = fmaxf(a, 0.f);
    }
    __syncthreads();
    for (int b = 0; b < 2; ++b) {
        float a = 0.f;
        for (int h = 0; h < 8; ++h) a += hid[b][h] * fc2[h * COUT + ch];
        attn[b * COUT + ch] = 1.f / (1.f + expf(-a));
    }
}

// ---------------------------------------------------------------------------
// Epilogue: out = relu(bn(x)*attn[b] + bn_skip(G[inv])), float4-vectorized.
// ---------------------------------------------------------------------------
__global__ __launch_bounds__(256) void final_kernel(
    float* __restrict__ out,
    const float* __restrict__ G,
    const int* __restrict__ inv_skip,
    const int* __restrict__ batch_of_out,
    const float* __restrict__ scale, const float* __restrict__ shift,
    const float* __restrict__ sscale, const float* __restrict__ sshift,
    const float* __restrict__ attn,
    int M)
{
    const int t  = threadIdx.x;
    const int c4 = (t & 31) * 4;
    const int rw = t >> 5;
    const float4 sc  = *(const float4*)&scale[c4];
    const float4 sh  = *(const float4*)&shift[c4];
    const float4 ssc = *(const float4*)&sscale[c4];
    const float4 ssh = *(const float4*)&sshift[c4];
    const float4 at0 = *(const float4*)&attn[c4];
    const float4 at1 = *(const float4*)&attn[COUT + c4];

    for (int m = blockIdx.x * 8 + rw; m < M; m += gridDim.x * 8) {
        const float4 x = *(const float4*)&out[(size_t)m * COUT + c4];
        const int b = batch_of_out[m];
        const int j = inv_skip[m];
        const float4 av = b ? at1 : at0;
        float4 y;
        y.x = (x.x * sc.x + sh.x) * av.x;
        y.y = (x.y * sc.y + sh.y) * av.y;
        y.z = (x.z * sc.z + sh.z) * av.z;
        y.w = (x.w * sc.w + sh.w) * av.w;
        if (j >= 0) {
            const float4 g = *(const float4*)&G[(size_t)j * COUT + c4];
            y.x += g.x * ssc.x + ssh.x;
            y.y += g.y * ssc.y + ssh.y;
            y.z += g.z * ssc.z + ssh.z;
            y.w += g.w * ssc.w + ssh.w;
        }
        y.x = y.x > 0.f ? y.x : 0.f;
        y.y = y.y > 0.f ? y.y : 0.f;
        y.z = y.z > 0.f ? y.z : 0.f;
        y.w = y.w > 0.f ? y.w : 0.f;
        *(float4*)&out[(size_t)m * COUT + c4] = y;
    }
}

extern "C" void kernel_launch(void* const* d_in, const int* in_sizes, int n_in,
                              void* d_out, int out_size, void* d_ws, size_t ws_size,
                              hipStream_t stream)
{
    const float* feats  = (const float*)d_in[0];
    const float* Wc     = (const float*)d_in[1];
    const float* Wsk    = (const float*)d_in[2];
    const float* gamma  = (const float*)d_in[3];
    const float* beta   = (const float*)d_in[4];
    const float* sgamma = (const float*)d_in[5];
    const float* sbeta  = (const float*)d_in[6];
    const float* fc1    = (const float*)d_in[7];
    const float* fc2    = (const float*)d_in[8];
    const int* cin_idx  = (const int*)d_in[9];
    const int* cout_idx = (const int*)d_in[10];
    const int* sin_idx  = (const int*)d_in[11];
    const int* sout_idx = (const int*)d_in[12];
    const int* boo      = (const int*)d_in[13];

    const int N  = in_sizes[0] / CIN;
    const int P  = in_sizes[9] / 9;
    const int Ls = in_sizes[11];
    const int M  = in_sizes[13];
    const int ntiles = (M + 63) / 64;

    float* out = (float*)d_out;

    // workspace layout
    char* ws = (char*)d_ws;
    __bf16* fb = (__bf16*)ws;                       // (N+1) x CIN
    size_t off = (size_t)(N + 1) * CIN * sizeof(__bf16);
    off = (off + 255) & ~(size_t)255;
    __bf16* wfrag = (__bf16*)(ws + off);
    off += (size_t)160 * 64 * 8 * sizeof(__bf16);
    off = (off + 255) & ~(size_t)255;
    int* tap_in = (int*)(ws + off);                 // 9 x M
    off += (size_t)9 * M * sizeof(int);
    off = (off + 255) & ~(size_t)255;
    float* G = (float*)(ws + off);                  // Ls x COUT
    off += (size_t)Ls * COUT * sizeof(float);
    int* inv_skip = (int*)(ws + off);               // M
    off += (size_t)M * sizeof(int);
    off = (off + 255) & ~(size_t)255;
    float* zstats = (float*)(ws + off);             // NC*384 + NSB*256
    off += (size_t)(NC * 384 + NSB * 256) * sizeof(float);
    int* msplit = (int*)(ws + off);
    off += 256;
    float* params = (float*)(ws + off);
    float* scale = params, *shift = params + 128;
    float* sscale = params + 256, *sshift = params + 384, *attn = params + 512;

    hipMemsetAsync(zstats, 0, (size_t)(NC * 384 + NSB * 256) * sizeof(float), stream);
    hipMemsetAsync(inv_skip, 0xFF, (size_t)M * sizeof(int), stream);      // -1
    hipMemsetAsync(tap_in, 0x7F, (size_t)9 * M * sizeof(int), stream);    // big sentinel

    // fused prep
    const int total8 = N * CIN / 8;
    const int nbA = (total8 + 255) / 256;
    const int nbB = (160 * 64 + 255) / 256;
    const int cpb = (P + 255) / 256;
    const int nbAB = nbA + nbB;
    const int nbABC = nbAB + 9 * cpb;
    const int nbABCD = nbABC + (Ls + 255) / 256;
    prep_kernel<<<nbABCD + 1, 256, 0, stream>>>(
        feats, fb, Wc, Wsk, wfrag, cin_idx, cout_idx, tap_in, sout_idx, inv_skip,
        boo, msplit, total8, P, cpb, Ls, N, M, nbA, nbAB, nbABC, nbABCD);

    conv_mfma_kernel<<<SKB + ntiles, 256, 0, stream>>>(
        fb, wfrag, tap_in, sin_idx, msplit, out, G, zstats, N, M, Ls);

    params_kernel<<<1, 128, 0, stream>>>(
        zstats, msplit, gamma, beta, sgamma, sbeta, fc1, fc2,
        scale, shift, sscale, sshift, attn, Ls, M);

    final_kernel<<<2048, 256, 0, stream>>>(
        out, G, inv_skip, boo, scale, shift, sscale, sshift, attn, M);
}

// Round 10
// 276.011 us; speedup vs baseline: 1.9039x; 1.0076x over previous
//
#include <hip/hip_runtime.h>

#define CIN 64
#define COUT 128
#define NC 64        // conv stat buckets
#define NSB 32       // skip stat buckets
#define LDT 132      // padded LDS row stride (dwords)
#define SKB 256      // skip role blocks

typedef __bf16 bf16x8 __attribute__((ext_vector_type(8)));
typedef float  f32x4  __attribute__((ext_vector_type(4)));
typedef __attribute__((address_space(3))) void lds_t;
typedef const __attribute__((address_space(1))) void glb_t;

// ---------------------------------------------------------------------------
// Fused prep: role-dispatch on blockIdx.x.
// ---------------------------------------------------------------------------
__global__ __launch_bounds__(256) void prep_kernel(
    const float* __restrict__ feats, __bf16* __restrict__ fb,
    const float* __restrict__ Wc, const float* __restrict__ Ws, __bf16* __restrict__ wf,
    const int* __restrict__ cin_idx, const int* __restrict__ cout_idx, int* __restrict__ tap_in,
    const int* __restrict__ sout, int* __restrict__ inv,
    const int* __restrict__ boo, int* __restrict__ msplit,
    int total8, int P, int cpb, int Ls, int N, int M,
    int nbA, int nbAB, int nbABC, int nbABCD)
{
    const int bid = blockIdx.x, t = threadIdx.x;
    if (bid < nbA) {                                  // A: feats -> bf16
        const int i = bid * 256 + t;
        if (i >= total8) return;
        const int i8 = i * 8;
        const float4 x0 = *(const float4*)(feats + i8);
        const float4 x1 = *(const float4*)(feats + i8 + 4);
        bf16x8 v;
        v[0] = (__bf16)x0.x; v[1] = (__bf16)x0.y; v[2] = (__bf16)x0.z; v[3] = (__bf16)x0.w;
        v[4] = (__bf16)x1.x; v[5] = (__bf16)x1.y; v[6] = (__bf16)x1.z; v[7] = (__bf16)x1.w;
        *(bf16x8*)(fb + i8) = v;
    } else if (bid < nbAB) {                          // B: wfrag pack
        const int id = (bid - nbA) * 256 + t;
        if (id >= 160 * 64) return;
        const int f = id >> 6, lane = id & 63;
        const float* W; int r;
        if (f < 144) { W = Wc + (size_t)(f >> 4) * CIN * COUT; r = f & 15; }
        else         { W = Ws;                                  r = f - 144; }
        const int c = r >> 1, s = r & 1;
        const int kbase = s * 32 + (lane >> 4) * 8;
        const int col = c * 16 + (lane & 15);
        bf16x8 v;
#pragma unroll
        for (int j = 0; j < 8; ++j) v[j] = (__bf16)W[(size_t)(kbase + j) * COUT + col];
        *(bf16x8*)(wf + ((size_t)f * 64 + lane) * 8) = v;
    } else if (bid < nbABC) {                         // C: tap scatter
        const int c = bid - nbAB;
        const int k = c / cpb;
        const int e = (c - k * cpb) * 256 + t;
        if (e >= P) return;
        const int oo = cout_idx[(size_t)k * P + e];
        if (oo < M) tap_in[(size_t)k * M + oo] = cin_idx[(size_t)k * P + e];
    } else if (bid < nbABCD) {                        // D: inverse skip map
        const int i = (bid - nbABC) * 256 + t;
        if (i < Ls) inv[sout[i]] = i;
    } else {                                          // tail: zero row + msplit
        if (t < 64) fb[(size_t)N * CIN + t] = (__bf16)0.f;
        if (t == 0) {
            int lo = 0, hi = M;
            while (lo < hi) { const int mid = (lo + hi) >> 1; if (boo[mid] < 1) lo = mid + 1; else hi = mid; }
            msplit[0] = lo;
        }
    }
}

// ---------------------------------------------------------------------------
// Fused conv + skip. Conv: 64 rows/block, 4 col-split waves. Per tap k:
// async global_load_lds stages 64 gathered rows (XOR-swizzled source, linear
// LDS dest), barrier, swizzled ds_read_b128 A-frags, 16 MFMA/wave.
// A-tile aliases the acc tile (acc used only in epilogue) -> 4 blocks/CU.
// ---------------------------------------------------------------------------
__global__ __launch_bounds__(256, 4) void conv_mfma_kernel(
    const __bf16* __restrict__ fb,      // [N+1][CIN], row N zeros
    const __bf16* __restrict__ wf,
    const int* __restrict__ tap_in,     // [9][M], 0x7f sentinel
    const int* __restrict__ sin_idx,
    const int* __restrict__ msplit_p,
    float* __restrict__ out,
    float* __restrict__ G,
    float* __restrict__ zstats,         // [NC*384 conv | NSB*256 skip]
    int N, int M, int Ls)
{
    __shared__ float acc[64 * LDT];     // epilogue tile; first 8KB doubles as A-tile
    __shared__ float sred[384];
    __bf16* Abuf = (__bf16*)acc;        // [64 rows][64 bf16], swizzled chunks
    const int t = threadIdx.x, lane = t & 63, wv = t >> 6;
    const int arow = lane & 15, apart = lane >> 4;

    if (blockIdx.x < SKB) {
        // ---------------- skip role ----------------
        const __bf16* wk = wf + ((size_t)144 * 64 + lane) * 8;
        const bf16x8 b00 = *(const bf16x8*)(wk + (size_t)(wv * 4 + 0) * 512);
        const bf16x8 b01 = *(const bf16x8*)(wk + (size_t)(wv * 4 + 1) * 512);
        const bf16x8 b10 = *(const bf16x8*)(wk + (size_t)(wv * 4 + 2) * 512);
        const bf16x8 b11 = *(const bf16x8*)(wk + (size_t)(wv * 4 + 3) * 512);
        const int colA = wv * 32 + arow;
        const int colB = colA + 16;

        float s1A = 0.f, s2A = 0.f, s1B = 0.f, s2B = 0.f;
        const int ngroups = (Ls + 15) >> 4;
        for (int g = blockIdx.x; g < ngroups; g += SKB) {
            const int e0 = g * 16;
            const int ea = e0 + arow;
            const int ii = (ea < Ls) ? sin_idx[ea] : 0;
            const __bf16* fr = fb + (size_t)ii * CIN + apart * 8;
            const bf16x8 a0 = *(const bf16x8*)fr;
            const bf16x8 a1 = *(const bf16x8*)(fr + 32);

            f32x4 dA = {0.f,0.f,0.f,0.f};
            f32x4 dB = {0.f,0.f,0.f,0.f};
            dA = __builtin_amdgcn_mfma_f32_16x16x32_bf16(a0, b00, dA, 0, 0, 0);
            dA = __builtin_amdgcn_mfma_f32_16x16x32_bf16(a1, b01, dA, 0, 0, 0);
            dB = __builtin_amdgcn_mfma_f32_16x16x32_bf16(a0, b10, dB, 0, 0, 0);
            dB = __builtin_amdgcn_mfma_f32_16x16x32_bf16(a1, b11, dB, 0, 0, 0);

            const int er = e0 + apart * 4;
#pragma unroll
            for (int j = 0; j < 4; ++j) {
                if (er + j < Ls) {
                    const float vA = dA[j], vB = dB[j];
                    G[(size_t)(er + j) * COUT + colA] = vA;
                    G[(size_t)(er + j) * COUT + colB] = vB;
                    s1A += vA; s2A += vA * vA;
                    s1B += vB; s2B += vB * vB;
                }
            }
        }
        s1A += __shfl_xor(s1A, 16); s1A += __shfl_xor(s1A, 32);
        s2A += __shfl_xor(s2A, 16); s2A += __shfl_xor(s2A, 32);
        s1B += __shfl_xor(s1B, 16); s1B += __shfl_xor(s1B, 32);
        s2B += __shfl_xor(s2B, 16); s2B += __shfl_xor(s2B, 32);
        if (apart == 0) {
            sred[colA] = s1A; sred[colB] = s1B;
            sred[128 + colA] = s2A; sred[128 + colB] = s2B;
        }
        __syncthreads();
        float* bucket = zstats + NC * 384 + (size_t)(blockIdx.x & (NSB - 1)) * 256;
        if (t < 128) {
            atomicAdd(&bucket[t],       sred[t]);
            atomicAdd(&bucket[128 + t], sred[128 + t]);
        }
        return;
    }

    // ---------------- conv role ----------------
    const int m0 = (blockIdx.x - SKB) * 64;
    const int msplit = msplit_p[0];
    for (int i = t; i < 384; i += 256) sred[i] = 0.f;

    const int l7 = lane & 7;
    // Preload all 9x2 tap indices (static-indexed registers).
    // Stage slot: wave wv stages rows wv*16 + (i*8 + (lane>>3)), chunk cs=lane&7.
    int idxv[9][2];
    const int mr0 = m0 + wv * 16 + (lane >> 3);
#pragma unroll
    for (int k = 0; k < 9; ++k) {
#pragma unroll
        for (int i = 0; i < 2; ++i) {
            const int mrow = mr0 + i * 8;
            int v = (mrow < M) ? tap_in[(size_t)k * M + mrow] : N;
            idxv[k][i] = (v > N) ? N : v;
        }
    }
    // XOR-swizzle: LDS slot (row r, cs) holds global chunk cg = cs ^ (r&7).
    // r&7 = lane>>3 for both i (i*8 preserves low 3 bits of r).
    const int goff = (l7 ^ (lane >> 3)) * 8;          // bf16 elems within row

    f32x4 d0[4], d1[4];
#pragma unroll
    for (int g = 0; g < 4; ++g) {
        d0[g] = (f32x4){0.f,0.f,0.f,0.f};
        d1[g] = (f32x4){0.f,0.f,0.f,0.f};
    }

    const int csr = (apart ^ l7) * 8;                 // read-side swizzled chunk (a0)

#pragma unroll
    for (int k = 0; k < 9; ++k) {
        // async stage: 64 rows x 128B, 2 instrs/wave, no dest VGPRs
        __builtin_amdgcn_global_load_lds(
            (glb_t*)(fb + (size_t)idxv[k][0] * CIN + goff),
            (lds_t*)(Abuf + wv * 1024), 16, 0, 0);
        __builtin_amdgcn_global_load_lds(
            (glb_t*)(fb + (size_t)idxv[k][1] * CIN + goff),
            (lds_t*)(Abuf + wv * 1024 + 512), 16, 0, 0);
        __syncthreads();                               // vmcnt(0) drain + barrier

        const __bf16* wb = wf + ((size_t)((k * 16 + wv * 4) * 64) + lane) * 8;
        const bf16x8 b00 = *(const bf16x8*)(wb + 0 * 512);
        const bf16x8 b01 = *(const bf16x8*)(wb + 1 * 512);
        const bf16x8 b10 = *(const bf16x8*)(wb + 2 * 512);
        const bf16x8 b11 = *(const bf16x8*)(wb + 3 * 512);

#pragma unroll
        for (int g = 0; g < 4; ++g) {
            const int base = (g * 16 + arow) * 64 + csr;
            const bf16x8 a0 = *(const bf16x8*)&Abuf[base];
            const bf16x8 a1 = *(const bf16x8*)&Abuf[base ^ 32];   // chunk cg+4
            d0[g] = __builtin_amdgcn_mfma_f32_16x16x32_bf16(a0, b00, d0[g], 0, 0, 0);
            d0[g] = __builtin_amdgcn_mfma_f32_16x16x32_bf16(a1, b01, d0[g], 0, 0, 0);
            d1[g] = __builtin_amdgcn_mfma_f32_16x16x32_bf16(a0, b10, d1[g], 0, 0, 0);
            d1[g] = __builtin_amdgcn_mfma_f32_16x16x32_bf16(a1, b11, d1[g], 0, 0, 0);
        }
        __syncthreads();                               // all reads done before next stage
    }

    // padded-LDS scatter (acc overwrites A-tile region: safe after barrier)
#pragma unroll
    for (int g = 0; g < 4; ++g)
#pragma unroll
        for (int j = 0; j < 4; ++j) {
            const int r = g * 16 + apart * 4 + j;
            acc[r * LDT + wv * 32 + arow]      = d0[g][j];
            acc[r * LDT + wv * 32 + 16 + arow] = d1[g][j];
        }
    __syncthreads();

    // coalesced store + fused BN stats
    const int c4 = (t & 31) * 4;
    const int r0 = t >> 5;
    float st_s[4] = {0.f,0.f,0.f,0.f};
    float st_q[4] = {0.f,0.f,0.f,0.f};
    float st_0[4] = {0.f,0.f,0.f,0.f};
#pragma unroll
    for (int i = 0; i < 8; ++i) {
        const int r = r0 + i * 8;
        const int m = m0 + r;
        if (m < M) {
            const f32x4 v = *(const f32x4*)&acc[r * LDT + c4];
            *(f32x4*)(out + (size_t)m * COUT + c4) = v;
            const bool b0 = m < msplit;
#pragma unroll
            for (int cc = 0; cc < 4; ++cc) {
                st_s[cc] += v[cc];
                st_q[cc] += v[cc] * v[cc];
                if (b0) st_0[cc] += v[cc];
            }
        }
    }
#pragma unroll
    for (int cc = 0; cc < 4; ++cc) {
        atomicAdd(&sred[c4 + cc],       st_0[cc]);
        atomicAdd(&sred[128 + c4 + cc], st_s[cc] - st_0[cc]);
        atomicAdd(&sred[256 + c4 + cc], st_q[cc]);
    }
    __syncthreads();
    float* bucket = zstats + (size_t)(blockIdx.x & (NC - 1)) * 384;
    if (t < 128) {
        atomicAdd(&bucket[t],       sred[t]);
        atomicAdd(&bucket[128 + t], sred[128 + t]);
        atomicAdd(&bucket[256 + t], sred[256 + t]);
    }
}

// ---------------------------------------------------------------------------
// Single-block: reduce buckets, BN params (main + skip), SE MLP.
// ---------------------------------------------------------------------------
__global__ __launch_bounds__(128) void params_kernel(
    const float* __restrict__ zstats,
    const int* __restrict__ msplit_p,
    const float* __restrict__ gamma, const float* __restrict__ beta,
    const float* __restrict__ sgamma, const float* __restrict__ sbeta,
    const float* __restrict__ fc1, const float* __restrict__ fc2,
    float* __restrict__ scale, float* __restrict__ shift,
    float* __restrict__ sscale, float* __restrict__ sshift,
    float* __restrict__ attn,
    int Ls, int M)
{
    __shared__ float desc[2][COUT];
    __shared__ float hid[2][8];
    const int ch = threadIdx.x;

    float s0 = 0.f, s1 = 0.f, q = 0.f;
    for (int b = 0; b < NC; ++b) {
        const float* st = zstats + (size_t)b * 384;
        s0 += st[ch]; s1 += st[128 + ch]; q += st[256 + ch];
    }
    float ss = 0.f, sq = 0.f;
    const float* sk = zstats + NC * 384;
    for (int b = 0; b < NSB; ++b) {
        ss += sk[(size_t)b * 256 + ch];
        sq += sk[(size_t)b * 256 + 128 + ch];
    }

    const float c0 = (float)msplit_p[0], c1 = (float)M - c0;
    const float Mf = (float)M;
    const float mu  = (s0 + s1) / Mf;
    const float var = q / Mf - mu * mu;
    const float rs  = rsqrtf(var + 1e-5f);
    const float sc  = rs * gamma[ch];
    const float sh  = beta[ch] - mu * sc;
    scale[ch] = sc;
    shift[ch] = sh;
    desc[0][ch] = (s0 / c0) * sc + sh;
    desc[1][ch] = (s1 / c1) * sc + sh;

    const float lsf  = (float)Ls;
    const float mus  = ss / lsf;
    const float vars = sq / lsf - mus * mus;
    const float rss  = rsqrtf(vars + 1e-5f);
    const float ssc  = rss * sgamma[ch];
    sscale[ch] = ssc;
    sshift[ch] = sbeta[ch] - mus * ssc;

    __syncthreads();
    if (ch < 16) {
        const int b = ch >> 3, h = ch & 7;
        float a = 0.f;
        for (int c = 0; c < COUT; ++c) a += desc[b][c] * fc1[c * 8 + h];
        hid[b][h] = fmaxf(a, 0.f);
    }
    __syncthreads();
    for (int b = 0; b < 2; ++b) {
        float a = 0.f;
        for (int h = 0; h < 8; ++h) a += hid[b][h] * fc2[h * COUT + ch];
        attn[b * COUT + ch] = 1.f / (1.f + expf(-a));
    }
}

// ---------------------------------------------------------------------------
// Epilogue: out = relu(bn(x)*attn[b] + bn_skip(G[inv])), float4-vectorized.
// ---------------------------------------------------------------------------
__global__ __launch_bounds__(256) void final_kernel(
    float* __restrict__ out,
    const float* __restrict__ G,
    const int* __restrict__ inv_skip,
    const int* __restrict__ batch_of_out,
    const float* __restrict__ scale, const float* __restrict__ shift,
    const float* __restrict__ sscale, const float* __restrict__ sshift,
    const float* __restrict__ attn,
    int M)
{
    const int t  = threadIdx.x;
    const int c4 = (t & 31) * 4;
    const int rw = t >> 5;
    const float4 sc  = *(const float4*)&scale[c4];
    const float4 sh  = *(const float4*)&shift[c4];
    const float4 ssc = *(const float4*)&sscale[c4];
    const float4 ssh = *(const float4*)&sshift[c4];
    const float4 at0 = *(const float4*)&attn[c4];
    const float4 at1 = *(const float4*)&attn[COUT + c4];

    for (int m = blockIdx.x * 8 + rw; m < M; m += gridDim.x * 8) {
        const float4 x = *(const float4*)&out[(size_t)m * COUT + c4];
        const int b = batch_of_out[m];
        const int j = inv_skip[m];
        const float4 av = b ? at1 : at0;
        float4 y;
        y.x = (x.x * sc.x + sh.x) * av.x;
        y.y = (x.y * sc.y + sh.y) * av.y;
        y.z = (x.z * sc.z + sh.z) * av.z;
        y.w = (x.w * sc.w + sh.w) * av.w;
        if (j >= 0) {
            const float4 g = *(const float4*)&G[(size_t)j * COUT + c4];
            y.x += g.x * ssc.x + ssh.x;
            y.y += g.y * ssc.y + ssh.y;
            y.z += g.z * ssc.z + ssh.z;
            y.w += g.w * ssc.w + ssh.w;
        }
        y.x = y.x > 0.f ? y.x : 0.f;
        y.y = y.y > 0.f ? y.y : 0.f;
        y.z = y.z > 0.f ? y.z : 0.f;
        y.w = y.w > 0.f ? y.w : 0.f;
        *(float4*)&out[(size_t)m * COUT + c4] = y;
    }
}

extern "C" void kernel_launch(void* const* d_in, const int* in_sizes, int n_in,
                              void* d_out, int out_size, void* d_ws, size_t ws_size,
                              hipStream_t stream)
{
    const float* feats  = (const float*)d_in[0];
    const float* Wc     = (const float*)d_in[1];
    const float* Wsk    = (const float*)d_in[2];
    const float* gamma  = (const float*)d_in[3];
    const float* beta   = (const float*)d_in[4];
    const float* sgamma = (const float*)d_in[5];
    const float* sbeta  = (const float*)d_in[6];
    const float* fc1    = (const float*)d_in[7];
    const float* fc2    = (const float*)d_in[8];
    const int* cin_idx  = (const int*)d_in[9];
    const int* cout_idx = (const int*)d_in[10];
    const int* sin_idx  = (const int*)d_in[11];
    const int* sout_idx = (const int*)d_in[12];
    const int* boo      = (const int*)d_in[13];

    const int N  = in_sizes[0] / CIN;
    const int P  = in_sizes[9] / 9;
    const int Ls = in_sizes[11];
    const int M  = in_sizes[13];
    const int ntiles = (M + 63) / 64;

    float* out = (float*)d_out;

    // workspace layout
    char* ws = (char*)d_ws;
    __bf16* fb = (__bf16*)ws;                       // (N+1) x CIN
    size_t off = (size_t)(N + 1) * CIN * sizeof(__bf16);
    off = (off + 255) & ~(size_t)255;
    __bf16* wfrag = (__bf16*)(ws + off);
    off += (size_t)160 * 64 * 8 * sizeof(__bf16);
    off = (off + 255) & ~(size_t)255;
    int* tap_in = (int*)(ws + off);                 // 9 x M
    off += (size_t)9 * M * sizeof(int);
    off = (off + 255) & ~(size_t)255;
    float* G = (float*)(ws + off);                  // Ls x COUT
    off += (size_t)Ls * COUT * sizeof(float);
    int* inv_skip = (int*)(ws + off);               // M
    off += (size_t)M * sizeof(int);
    off = (off + 255) & ~(size_t)255;
    float* zstats = (float*)(ws + off);             // NC*384 + NSB*256
    off += (size_t)(NC * 384 + NSB * 256) * sizeof(float);
    int* msplit = (int*)(ws + off);
    off += 256;
    float* params = (float*)(ws + off);
    float* scale = params, *shift = params + 128;
    float* sscale = params + 256, *sshift = params + 384, *attn = params + 512;

    hipMemsetAsync(zstats, 0, (size_t)(NC * 384 + NSB * 256) * sizeof(float), stream);
    hipMemsetAsync(inv_skip, 0xFF, (size_t)M * sizeof(int), stream);      // -1
    hipMemsetAsync(tap_in, 0x7F, (size_t)9 * M * sizeof(int), stream);    // big sentinel

    // fused prep
    const int total8 = N * CIN / 8;
    const int nbA = (total8 + 255) / 256;
    const int nbB = (160 * 64 + 255) / 256;
    const int cpb = (P + 255) / 256;
    const int nbAB = nbA + nbB;
    const int nbABC = nbAB + 9 * cpb;
    const int nbABCD = nbABC + (Ls + 255) / 256;
    prep_kernel<<<nbABCD + 1, 256, 0, stream>>>(
        feats, fb, Wc, Wsk, wfrag, cin_idx, cout_idx, tap_in, sout_idx, inv_skip,
        boo, msplit, total8, P, cpb, Ls, N, M, nbA, nbAB, nbABC, nbABCD);

    conv_mfma_kernel<<<SKB + ntiles, 256, 0, stream>>>(
        fb, wfrag, tap_in, sin_idx, msplit, out, G, zstats, N, M, Ls);

    params_kernel<<<1, 128, 0, stream>>>(
        zstats, msplit, gamma, beta, sgamma, sbeta, fc1, fc2,
        scale, shift, sscale, sshift, attn, Ls, M);

    final_kernel<<<2048, 256, 0, stream>>>(
        out, G, inv_skip, boo, scale, shift, sscale, sshift, attn, M);
}